// Round 1
// baseline (160.946 us; speedup 1.0000x reference)
//
#include <hip/hip_runtime.h>
#include <hip/hip_bf16.h>

#define Bn 8
#define Cn 3
#define Tn 32
#define Hn 128
#define Wn 128
#define HWn (Hn * Wn)          // 16384
#define Nn (Tn * HWn)          // 524288 elems per (b,c)
#define EPSn 1e-5f

__device__ __forceinline__ float silu_f(float v) {
    return v / (1.0f + __expf(-v));
}

// ---------------- K1: spatial 3x3 conv (1 -> 3 ch) + SiLU -> y[b,c,t,h,w] ----------------
__global__ __launch_bounds__(256) void k1_spatial(
    const float* __restrict__ x, const float* __restrict__ wsp,
    const float* __restrict__ bsp, float* __restrict__ y)
{
    const int bt = blockIdx.x;          // b*T + t, 0..255
    const int h0 = blockIdx.y * 16;     // 8 tiles of 16 rows
    __shared__ float tile[18 * 130];
    const float* xp = x + (size_t)bt * HWn;
    for (int i = threadIdx.x; i < 18 * 130; i += 256) {
        int r = i / 130, cc = i % 130;
        int gh = h0 + r - 1, gw = cc - 1;
        float v = 0.0f;
        if (gh >= 0 && gh < Hn && gw >= 0 && gw < Wn) v = xp[gh * Wn + gw];
        tile[i] = v;
    }
    float w[27], bb[3];
#pragma unroll
    for (int i = 0; i < 27; ++i) w[i] = wsp[i];
    bb[0] = bsp[0]; bb[1] = bsp[1]; bb[2] = bsp[2];
    __syncthreads();
    const int b = bt >> 5, t = bt & 31;
    const int wc = threadIdx.x & 127;
    const int hsub = threadIdx.x >> 7;  // 0 or 1
    for (int rr = 0; rr < 8; ++rr) {
        int hl = rr * 2 + hsub;         // 0..15
        float a0 = bb[0], a1 = bb[1], a2 = bb[2];
#pragma unroll
        for (int i = 0; i < 3; ++i) {
#pragma unroll
            for (int j = 0; j < 3; ++j) {
                float v = tile[(hl + i) * 130 + wc + j];
                a0 += w[0 * 9 + i * 3 + j] * v;
                a1 += w[1 * 9 + i * 3 + j] * v;
                a2 += w[2 * 9 + i * 3 + j] * v;
            }
        }
        int gh = h0 + hl;
        size_t o0 = ((size_t)(b * Cn + 0) * Tn + t) * HWn + (size_t)gh * Wn + wc;
        y[o0] = silu_f(a0);
        y[o0 + (size_t)Tn * HWn] = silu_f(a1);
        y[o0 + 2 * (size_t)Tn * HWn] = silu_f(a2);
    }
}

// ------- K2: temporal depthwise 7-tap conv + SiLU + SiLU -> g (into d_out); partials -------
// partials[blk] = {sum g, sum g^2, sum_s g*wkt0[s], sum_s g*wkt1[s]} for blk = bc*T + t
__global__ __launch_bounds__(256) void k2_temporal(
    const float* __restrict__ y, const float* __restrict__ wtp,
    const float* __restrict__ btp, const float* __restrict__ wkt,
    float* __restrict__ g, float4* __restrict__ partials)
{
    const int blk = blockIdx.x;         // bc*T + t
    const int t = blk & 31;
    const int bc = blk >> 5;
    const int c = bc % Cn;
    float wt[7];
#pragma unroll
    for (int k = 0; k < 7; ++k) wt[k] = wtp[c * 7 + k];
    const float bias = btp[c];
    const float* yrow = y + (size_t)bc * Tn * HWn;
    float* grow = g + (size_t)blk * HWn;
    const int tid = threadIdx.x;
    float lsum = 0.f, lsq = 0.f, lt0 = 0.f, lt1 = 0.f;
    for (int s = tid * 4; s < HWn; s += 256 * 4) {
        float ax = bias, ay = bias, az = bias, aw = bias;
#pragma unroll
        for (int k = 0; k < 7; ++k) {
            int tt = t + k - 3;
            if ((unsigned)tt < (unsigned)Tn) {
                float4 yv = *(const float4*)(yrow + (size_t)tt * HWn + s);
                ax += wt[k] * yv.x; ay += wt[k] * yv.y;
                az += wt[k] * yv.z; aw += wt[k] * yv.w;
            }
        }
        ax = silu_f(silu_f(ax)); ay = silu_f(silu_f(ay));
        az = silu_f(silu_f(az)); aw = silu_f(silu_f(aw));
        float4 gv; gv.x = ax; gv.y = ay; gv.z = az; gv.w = aw;
        *(float4*)(grow + s) = gv;
        float4 k0 = *(const float4*)(wkt + s);
        float4 k1 = *(const float4*)(wkt + HWn + s);
        lsum += ax + ay + az + aw;
        lsq  += ax * ax + ay * ay + az * az + aw * aw;
        lt0  += k0.x * ax + k0.y * ay + k0.z * az + k0.w * aw;
        lt1  += k1.x * ax + k1.y * ay + k1.z * az + k1.w * aw;
    }
    __shared__ float4 red[256];
    float4 mine; mine.x = lsum; mine.y = lsq; mine.z = lt0; mine.w = lt1;
    red[tid] = mine;
    __syncthreads();
    for (int off = 128; off > 0; off >>= 1) {
        if (tid < off) {
            float4 a = red[tid], bq = red[tid + off];
            a.x += bq.x; a.y += bq.y; a.z += bq.z; a.w += bq.w;
            red[tid] = a;
        }
        __syncthreads();
    }
    if (tid == 0) partials[blk] = red[0];
}

// ------------- K3: SwitchNorm stats + kv_t finalize + softmax over t -> A -------------
__global__ __launch_bounds__(256) void k3_finalize(
    const float4* __restrict__ partials, const float* __restrict__ mean_w,
    const float* __restrict__ var_w, const float* __restrict__ snw,
    const float* __restrict__ snb, const float* __restrict__ wkt,
    const float* __restrict__ wks, float* __restrict__ scale,
    float* __restrict__ shift, float* __restrict__ A, float* __restrict__ wsum)
{
    const int tid = threadIdx.x;
    __shared__ float red0[256], red1[256];
    float l0 = 0.f, l1 = 0.f;
    for (int i = tid; i < HWn; i += 256) { l0 += wkt[i]; l1 += wkt[HWn + i]; }
    red0[tid] = l0; red1[tid] = l1;
    __syncthreads();
    for (int off = 128; off > 0; off >>= 1) {
        if (tid < off) { red0[tid] += red0[tid + off]; red1[tid] += red1[tid + off]; }
        __syncthreads();
    }
    __shared__ float sWt0, sWt1, sWs0, sWs1;
    __shared__ float sh_mean[24], sh_var[24], sh_temp[24];
    __shared__ float sh_mln[8], sh_vln[8], sh_mbn[3], sh_vbn[3];
    __shared__ float sh_mw[3], sh_vw[3];
    __shared__ float sh_scale[24], sh_shift[24];
    if (tid == 0) {
        sWt0 = red0[0]; sWt1 = red1[0];
        float a = 0.f, b = 0.f;
        for (int t = 0; t < Tn; ++t) { a += wks[t]; b += wks[Tn + t]; }
        sWs0 = a; sWs1 = b;
        wsum[0] = sWt0; wsum[1] = sWt1; wsum[2] = a; wsum[3] = b;
    }
    if (tid < 24) {
        float S = 0.f, SS = 0.f;
        for (int t = 0; t < Tn; ++t) {
            float4 p = partials[tid * Tn + t];
            S += p.x; SS += p.y;
        }
        const float Nf = (float)Nn;
        float mean = S / Nf;
        float var = (SS - S * mean) / (Nf - 1.0f);   // unbiased (ddof=1)
        sh_mean[tid] = mean; sh_var[tid] = var; sh_temp[tid] = var + mean * mean;
    }
    __syncthreads();
    if (tid == 0) {
        for (int b = 0; b < Bn; ++b) {
            float m = 0.f, tp = 0.f;
            for (int c = 0; c < Cn; ++c) { m += sh_mean[b * 3 + c]; tp += sh_temp[b * 3 + c]; }
            m *= (1.0f / 3.0f); tp *= (1.0f / 3.0f);
            sh_mln[b] = m; sh_vln[b] = tp - m * m;
        }
        for (int c = 0; c < Cn; ++c) {
            float m = 0.f, tp = 0.f;
            for (int b = 0; b < Bn; ++b) { m += sh_mean[b * 3 + c]; tp += sh_temp[b * 3 + c]; }
            m *= 0.125f; tp *= 0.125f;
            sh_mbn[c] = m; sh_vbn[c] = tp - m * m;
        }
        {
            float m0 = mean_w[0], m1 = mean_w[1], m2 = mean_w[2];
            float mm = fmaxf(m0, fmaxf(m1, m2));
            float e0 = __expf(m0 - mm), e1 = __expf(m1 - mm), e2 = __expf(m2 - mm);
            float inv = 1.0f / (e0 + e1 + e2);
            sh_mw[0] = e0 * inv; sh_mw[1] = e1 * inv; sh_mw[2] = e2 * inv;
        }
        {
            float v0 = var_w[0], v1 = var_w[1], v2 = var_w[2];
            float vm = fmaxf(v0, fmaxf(v1, v2));
            float e0 = __expf(v0 - vm), e1 = __expf(v1 - vm), e2 = __expf(v2 - vm);
            float inv = 1.0f / (e0 + e1 + e2);
            sh_vw[0] = e0 * inv; sh_vw[1] = e1 * inv; sh_vw[2] = e2 * inv;
        }
    }
    __syncthreads();
    if (tid < 24) {
        int b = tid / 3, c = tid % 3;
        float mean = sh_mw[0] * sh_mean[tid] + sh_mw[1] * sh_mln[b] + sh_mw[2] * sh_mbn[c];
        float var  = sh_vw[0] * sh_var[tid]  + sh_vw[1] * sh_vln[b] + sh_vw[2] * sh_vbn[c];
        float inv = 1.0f / sqrtf(var + EPSn);
        float sc = inv * snw[c];
        float sf = snb[c] - mean * sc;
        sh_scale[tid] = sc; sh_shift[tid] = sf;
        scale[tid] = sc; shift[tid] = sf;
    }
    __syncthreads();
    __shared__ float kvt0[Bn * Cn * Tn], kvt1[Bn * Cn * Tn];
    for (int i = tid; i < Bn * Cn * Tn; i += 256) {
        int bc = i >> 5;
        float4 p = partials[i];
        kvt0[i] = sh_scale[bc] * p.z + sh_shift[bc] * sWt0;
        kvt1[i] = sh_scale[bc] * p.w + sh_shift[bc] * sWt1;
    }
    __syncthreads();
    if (tid < 24) {
        float m = -3.4e38f;
        for (int t = 0; t < Tn; ++t) m = fmaxf(m, kvt0[tid * Tn + t]);
        float se = 0.f;
        for (int t = 0; t < Tn; ++t) se += __expf(kvt0[tid * Tn + t] - m);
        float inv = 1.0f / se;
        for (int t = 0; t < Tn; ++t)
            A[tid * Tn + t] = sqrtf(__expf(kvt0[tid * Tn + t] - m) * inv) * kvt1[tid * Tn + t];
    }
}

// ------------- K4: kv_s contraction over t, with affine fixup -> kv0, kv1 -------------
__global__ __launch_bounds__(256) void k4_kvs(
    const float* __restrict__ g, const float* __restrict__ wks,
    const float* __restrict__ scale, const float* __restrict__ shift,
    const float* __restrict__ wsum, float* __restrict__ kv0, float* __restrict__ kv1)
{
    const int bc = blockIdx.y;       // 24
    const int chunk = blockIdx.x;    // 8
    const int tid = threadIdx.x;
    __shared__ float w0[Tn], w1[Tn];
    if (tid < Tn) { w0[tid] = wks[tid]; w1[tid] = wks[Tn + tid]; }
    __syncthreads();
    const int s = chunk * 2048 + tid * 8;
    const float* gp = g + (size_t)bc * Tn * HWn + s;
    float a0x=0,a0y=0,a0z=0,a0w=0, b0x=0,b0y=0,b0z=0,b0w=0;
    float a1x=0,a1y=0,a1z=0,a1w=0, b1x=0,b1y=0,b1z=0,b1w=0;
    for (int t = 0; t < Tn; ++t) {
        float4 ga = *(const float4*)(gp + (size_t)t * HWn);
        float4 gb = *(const float4*)(gp + (size_t)t * HWn + 4);
        float wa = w0[t], wb = w1[t];
        a0x += wa * ga.x; a0y += wa * ga.y; a0z += wa * ga.z; a0w += wa * ga.w;
        b0x += wa * gb.x; b0y += wa * gb.y; b0z += wa * gb.z; b0w += wa * gb.w;
        a1x += wb * ga.x; a1y += wb * ga.y; a1z += wb * ga.z; a1w += wb * ga.w;
        b1x += wb * gb.x; b1y += wb * gb.y; b1z += wb * gb.z; b1w += wb * gb.w;
    }
    const float sc = scale[bc], sf = shift[bc];
    const float c0 = sf * wsum[2], c1 = sf * wsum[3];
    float4 o;
    o.x = sc*a0x + c0; o.y = sc*a0y + c0; o.z = sc*a0z + c0; o.w = sc*a0w + c0;
    *(float4*)(kv0 + (size_t)bc * HWn + s) = o;
    o.x = sc*b0x + c0; o.y = sc*b0y + c0; o.z = sc*b0z + c0; o.w = sc*b0w + c0;
    *(float4*)(kv0 + (size_t)bc * HWn + s + 4) = o;
    o.x = sc*a1x + c1; o.y = sc*a1y + c1; o.z = sc*a1z + c1; o.w = sc*a1w + c1;
    *(float4*)(kv1 + (size_t)bc * HWn + s) = o;
    o.x = sc*b1x + c1; o.y = sc*b1y + c1; o.z = sc*b1z + c1; o.w = sc*b1w + c1;
    *(float4*)(kv1 + (size_t)bc * HWn + s + 4) = o;
}

// ------------- K5: softmax over s (per bc row) -> B[s] = sqrt(ks)*vs -------------
__global__ __launch_bounds__(256) void k5_softmax_s(
    const float* __restrict__ kv0, const float* __restrict__ kv1, float* __restrict__ Bv)
{
    const int bc = blockIdx.x;
    const int tid = threadIdx.x;
    const float* p0 = kv0 + (size_t)bc * HWn;
    const float* p1 = kv1 + (size_t)bc * HWn;
    float* bp = Bv + (size_t)bc * HWn;
    __shared__ float red[256];
    float m = -3.4e38f;
    for (int i = tid; i < HWn; i += 256) m = fmaxf(m, p0[i]);
    red[tid] = m;
    __syncthreads();
    for (int off = 128; off > 0; off >>= 1) {
        if (tid < off) red[tid] = fmaxf(red[tid], red[tid + off]);
        __syncthreads();
    }
    __shared__ float smax, ssum;
    if (tid == 0) smax = red[0];
    __syncthreads();
    float mx = smax;
    float se = 0.f;
    for (int i = tid; i < HWn; i += 256) se += __expf(p0[i] - mx);
    __syncthreads();
    red[tid] = se;
    __syncthreads();
    for (int off = 128; off > 0; off >>= 1) {
        if (tid < off) red[tid] += red[tid + off];
        __syncthreads();
    }
    if (tid == 0) ssum = red[0];
    __syncthreads();
    const float inv = 1.0f / ssum;
    for (int i = tid; i < HWn; i += 256)
        bp[i] = sqrtf(__expf(p0[i] - mx) * inv) * p1[i];
}

// ------------- K6: out[bc,t,s] = A[bc,t] * B[bc,s] -------------
__global__ __launch_bounds__(256) void k6_outer(
    const float* __restrict__ A, const float* __restrict__ Bv, float* __restrict__ out)
{
    const int bc = blockIdx.y;       // 24
    const int chunk = blockIdx.x;    // 16 chunks of 1024
    const int tid = threadIdx.x;
    __shared__ float a[Tn];
    if (tid < Tn) a[tid] = A[bc * Tn + tid];
    __syncthreads();
    const int s = chunk * 1024 + tid * 4;
    float4 b4 = *(const float4*)(Bv + (size_t)bc * HWn + s);
    float* op = out + (size_t)bc * Tn * HWn + s;
#pragma unroll
    for (int t = 0; t < Tn; ++t) {
        float av = a[t];
        float4 o;
        o.x = av * b4.x; o.y = av * b4.y; o.z = av * b4.z; o.w = av * b4.w;
        *(float4*)(op + (size_t)t * HWn) = o;
    }
}

extern "C" void kernel_launch(void* const* d_in, const int* in_sizes, int n_in,
                              void* d_out, int out_size, void* d_ws, size_t ws_size,
                              hipStream_t stream) {
    const float* x          = (const float*)d_in[0];
    const float* w_spatial  = (const float*)d_in[1];
    const float* b_spatial  = (const float*)d_in[2];
    const float* w_temporal = (const float*)d_in[3];
    const float* b_temporal = (const float*)d_in[4];
    const float* sn_weight  = (const float*)d_in[5];
    const float* sn_bias    = (const float*)d_in[6];
    const float* mean_weight= (const float*)d_in[7];
    const float* var_weight = (const float*)d_in[8];
    const float* w_kv_s     = (const float*)d_in[9];
    const float* w_kv_t     = (const float*)d_in[10];
    float* out = (float*)d_out;
    float* ws  = (float*)d_ws;

    const size_t ysz = (size_t)Bn * Cn * Tn * HWn;   // 12,582,912 floats
    float*  y        = ws;
    float4* partials = (float4*)(ws + ysz);                        // 768 float4
    float*  scale    = ws + ysz + 4 * (size_t)(Bn * Cn * Tn);      // 24
    float*  shift    = scale + 24;                                 // 24
    float*  A        = shift + 24;                                 // 768
    float*  wsum     = A + (size_t)(Bn * Cn * Tn);                 // 4
    // kv0/kv1/Bv reuse the y region (y is dead after k2)
    float*  kv0 = ws;
    float*  kv1 = ws + (size_t)Bn * Cn * HWn;
    float*  Bv  = ws + 2 * (size_t)Bn * Cn * HWn;
    float*  g   = out;   // d_out doubles as scratch for g until k6 overwrites it

    k1_spatial<<<dim3(Bn * Tn, Hn / 16), 256, 0, stream>>>(x, w_spatial, b_spatial, y);
    k2_temporal<<<Bn * Cn * Tn, 256, 0, stream>>>(y, w_temporal, b_temporal, w_kv_t,
                                                  g, partials);
    k3_finalize<<<1, 256, 0, stream>>>(partials, mean_weight, var_weight, sn_weight,
                                       sn_bias, w_kv_t, w_kv_s, scale, shift, A, wsum);
    k4_kvs<<<dim3(8, Bn * Cn), 256, 0, stream>>>(g, w_kv_s, scale, shift, wsum, kv0, kv1);
    k5_softmax_s<<<Bn * Cn, 256, 0, stream>>>(kv0, kv1, Bv);
    k6_outer<<<dim3(16, Bn * Cn), 256, 0, stream>>>(A, Bv, out);
}

// Round 2
// 109.341 us; speedup vs baseline: 1.4720x; 1.4720x over previous
//
#include <hip/hip_runtime.h>
#include <hip/hip_bf16.h>

#define Bn 8
#define Cn 3
#define Tn 32
#define Hn 128
#define Wn 128
#define HWn (Hn * Wn)          // 16384
#define Nn (Tn * HWn)          // 524288 elems per (b,c)
#define EPSn 1e-5f
#define NCHUNK 16              // s-chunks in k2 (1024 floats each)

__device__ __forceinline__ float silu_f(float v) {
    return v / (1.0f + __expf(-v));
}

// ---------------- K1: spatial 3x3 conv (1 -> 3 ch) + SiLU -> y[b,c,t,h,w] ----------------
__global__ __launch_bounds__(256) void k1_spatial(
    const float* __restrict__ x, const float* __restrict__ wsp,
    const float* __restrict__ bsp, float* __restrict__ y)
{
    const int bt = blockIdx.x;          // b*T + t, 0..255
    const int h0 = blockIdx.y * 16;     // 8 tiles of 16 rows
    __shared__ float tile[18 * 130];
    const float* xp = x + (size_t)bt * HWn;
    for (int i = threadIdx.x; i < 18 * 130; i += 256) {
        int r = i / 130, cc = i % 130;
        int gh = h0 + r - 1, gw = cc - 1;
        float v = 0.0f;
        if (gh >= 0 && gh < Hn && gw >= 0 && gw < Wn) v = xp[gh * Wn + gw];
        tile[i] = v;
    }
    float w[27], bb[3];
#pragma unroll
    for (int i = 0; i < 27; ++i) w[i] = wsp[i];
    bb[0] = bsp[0]; bb[1] = bsp[1]; bb[2] = bsp[2];
    __syncthreads();
    const int b = bt >> 5, t = bt & 31;
    const int wc = threadIdx.x & 127;
    const int hsub = threadIdx.x >> 7;  // 0 or 1
    for (int rr = 0; rr < 8; ++rr) {
        int hl = rr * 2 + hsub;         // 0..15
        float a0 = bb[0], a1 = bb[1], a2 = bb[2];
#pragma unroll
        for (int i = 0; i < 3; ++i) {
#pragma unroll
            for (int j = 0; j < 3; ++j) {
                float v = tile[(hl + i) * 130 + wc + j];
                a0 += w[0 * 9 + i * 3 + j] * v;
                a1 += w[1 * 9 + i * 3 + j] * v;
                a2 += w[2 * 9 + i * 3 + j] * v;
            }
        }
        int gh = h0 + hl;
        size_t o0 = ((size_t)(b * Cn + 0) * Tn + t) * HWn + (size_t)gh * Wn + wc;
        y[o0] = silu_f(a0);
        y[o0 + (size_t)Tn * HWn] = silu_f(a1);
        y[o0 + 2 * (size_t)Tn * HWn] = silu_f(a2);
    }
}

// ------- K2: temporal conv streamed over t (ring buffer, y read once) + fused analytics -----
// Per block (bc, chunk of 1024 s): for each t computes g = silu(silu(tconv)), accumulates
//   per-t wave-reduced partials {sum g, sum g^2, sum_s g*wkt0, sum_s g*wkt1} -> partials
//   per-s contractions over t {sum_t wks0[t]*g, sum_t wks1[t]*g}           -> raw0/raw1
// g itself is never written (output is rank-1: A[t]*B[s]).
__global__ __launch_bounds__(256) void k2_temporal(
    const float* __restrict__ y, const float* __restrict__ wtp,
    const float* __restrict__ btp, const float* __restrict__ wkt,
    const float* __restrict__ wks,
    float* __restrict__ raw0, float* __restrict__ raw1, float4* __restrict__ partials)
{
    const int chunk = blockIdx.x;       // 0..15
    const int bc = blockIdx.y;          // 0..23
    const int c = bc % Cn;
    const int tid = threadIdx.x;
    const int lane = tid & 63;
    const int wave = tid >> 6;

    float wt[7];
#pragma unroll
    for (int k = 0; k < 7; ++k) wt[k] = wtp[c * 7 + k];
    const float bias = btp[c];

    __shared__ float w0s[Tn], w1s[Tn];
    if (tid < Tn) { w0s[tid] = wks[tid]; w1s[tid] = wks[Tn + tid]; }
    __shared__ float4 wred[Tn][4];

    const int s = chunk * 1024 + tid * 4;
    const float* yp = y + (size_t)bc * Nn + s;
    const float4 k0v = *(const float4*)(wkt + s);
    const float4 k1v = *(const float4*)(wkt + HWn + s);

    float4 ring[7];
    float a0x = 0.f, a0y = 0.f, a0z = 0.f, a0w = 0.f;
    float a1x = 0.f, a1y = 0.f, a1z = 0.f, a1w = 0.f;
    __syncthreads();

#pragma unroll
    for (int tt = 0; tt < Tn + 3; ++tt) {
        if (tt < Tn) ring[tt % 7] = *(const float4*)(yp + (size_t)tt * HWn);
        if (tt >= 3) {
            const int to = tt - 3;
            float gx = bias, gy = bias, gz = bias, gw = bias;
#pragma unroll
            for (int k = 0; k < 7; ++k) {
                const int ts = to + k - 3;
                if (ts >= 0 && ts < Tn) {
                    const float4 v = ring[((unsigned)ts) % 7u];
                    const float wk = wt[k];
                    gx += wk * v.x; gy += wk * v.y; gz += wk * v.z; gw += wk * v.w;
                }
            }
            gx = silu_f(silu_f(gx)); gy = silu_f(silu_f(gy));
            gz = silu_f(silu_f(gz)); gw = silu_f(silu_f(gw));
            // kv_s accumulation (contraction over t)
            const float w0 = w0s[to], w1 = w1s[to];
            a0x += w0 * gx; a0y += w0 * gy; a0z += w0 * gz; a0w += w0 * gw;
            a1x += w1 * gx; a1y += w1 * gy; a1z += w1 * gz; a1w += w1 * gw;
            // per-t partials
            float psum = gx + gy + gz + gw;
            float psq  = gx * gx + gy * gy + gz * gz + gw * gw;
            float pt0  = k0v.x * gx + k0v.y * gy + k0v.z * gz + k0v.w * gw;
            float pt1  = k1v.x * gx + k1v.y * gy + k1v.z * gz + k1v.w * gw;
#pragma unroll
            for (int m = 1; m < 64; m <<= 1) {
                psum += __shfl_xor(psum, m, 64);
                psq  += __shfl_xor(psq,  m, 64);
                pt0  += __shfl_xor(pt0,  m, 64);
                pt1  += __shfl_xor(pt1,  m, 64);
            }
            if (lane == 0) {
                float4 p; p.x = psum; p.y = psq; p.z = pt0; p.w = pt1;
                wred[to][wave] = p;
            }
        }
    }
    __syncthreads();
    if (tid < Tn) {
        float4 a = wred[tid][0], b1 = wred[tid][1], b2 = wred[tid][2], b3 = wred[tid][3];
        a.x += b1.x + b2.x + b3.x; a.y += b1.y + b2.y + b3.y;
        a.z += b1.z + b2.z + b3.z; a.w += b1.w + b2.w + b3.w;
        partials[(bc * NCHUNK + chunk) * Tn + tid] = a;
    }
    float4 o;
    o.x = a0x; o.y = a0y; o.z = a0z; o.w = a0w;
    *(float4*)(raw0 + (size_t)bc * HWn + s) = o;
    o.x = a1x; o.y = a1y; o.z = a1z; o.w = a1w;
    *(float4*)(raw1 + (size_t)bc * HWn + s) = o;
}

// ------------- K3: reduce chunk partials + SwitchNorm stats + kv_t softmax -> A -------------
__global__ __launch_bounds__(256) void k3_finalize(
    const float4* __restrict__ partials, const float* __restrict__ mean_w,
    const float* __restrict__ var_w, const float* __restrict__ snw,
    const float* __restrict__ snb, const float* __restrict__ wkt,
    const float* __restrict__ wks, float* __restrict__ scale,
    float* __restrict__ shift, float* __restrict__ A, float* __restrict__ wsum)
{
    const int tid = threadIdx.x;
    __shared__ float4 tsum[Bn * Cn * Tn];     // [bc][t], 12 KB
    for (int i = tid; i < Bn * Cn * Tn; i += 256) {
        const int bc = i >> 5, t = i & 31;
        float4 acc; acc.x = 0.f; acc.y = 0.f; acc.z = 0.f; acc.w = 0.f;
        for (int ch = 0; ch < NCHUNK; ++ch) {
            float4 p = partials[(bc * NCHUNK + ch) * Tn + t];
            acc.x += p.x; acc.y += p.y; acc.z += p.z; acc.w += p.w;
        }
        tsum[i] = acc;
    }
    __shared__ float red0[256], red1[256];
    float l0 = 0.f, l1 = 0.f;
    for (int i = tid; i < HWn; i += 256) { l0 += wkt[i]; l1 += wkt[HWn + i]; }
    red0[tid] = l0; red1[tid] = l1;
    __syncthreads();
    for (int off = 128; off > 0; off >>= 1) {
        if (tid < off) { red0[tid] += red0[tid + off]; red1[tid] += red1[tid + off]; }
        __syncthreads();
    }
    __shared__ float sWt0, sWt1;
    __shared__ float sh_mean[24], sh_var[24], sh_temp[24];
    __shared__ float sh_mln[8], sh_vln[8], sh_mbn[3], sh_vbn[3];
    __shared__ float sh_mw[3], sh_vw[3];
    __shared__ float sh_scale[24], sh_shift[24];
    if (tid == 0) {
        sWt0 = red0[0]; sWt1 = red1[0];
        float a = 0.f, b = 0.f;
        for (int t = 0; t < Tn; ++t) { a += wks[t]; b += wks[Tn + t]; }
        wsum[0] = sWt0; wsum[1] = sWt1; wsum[2] = a; wsum[3] = b;
    }
    if (tid < 24) {
        float S = 0.f, SS = 0.f;
        for (int t = 0; t < Tn; ++t) {
            float4 p = tsum[tid * Tn + t];
            S += p.x; SS += p.y;
        }
        const float Nf = (float)Nn;
        float mean = S / Nf;
        float var = (SS - S * mean) / (Nf - 1.0f);   // unbiased (ddof=1)
        sh_mean[tid] = mean; sh_var[tid] = var; sh_temp[tid] = var + mean * mean;
    }
    __syncthreads();
    if (tid == 0) {
        for (int b = 0; b < Bn; ++b) {
            float m = 0.f, tp = 0.f;
            for (int c = 0; c < Cn; ++c) { m += sh_mean[b * 3 + c]; tp += sh_temp[b * 3 + c]; }
            m *= (1.0f / 3.0f); tp *= (1.0f / 3.0f);
            sh_mln[b] = m; sh_vln[b] = tp - m * m;
        }
        for (int c = 0; c < Cn; ++c) {
            float m = 0.f, tp = 0.f;
            for (int b = 0; b < Bn; ++b) { m += sh_mean[b * 3 + c]; tp += sh_temp[b * 3 + c]; }
            m *= 0.125f; tp *= 0.125f;
            sh_mbn[c] = m; sh_vbn[c] = tp - m * m;
        }
        {
            float m0 = mean_w[0], m1 = mean_w[1], m2 = mean_w[2];
            float mm = fmaxf(m0, fmaxf(m1, m2));
            float e0 = __expf(m0 - mm), e1 = __expf(m1 - mm), e2 = __expf(m2 - mm);
            float inv = 1.0f / (e0 + e1 + e2);
            sh_mw[0] = e0 * inv; sh_mw[1] = e1 * inv; sh_mw[2] = e2 * inv;
        }
        {
            float v0 = var_w[0], v1 = var_w[1], v2 = var_w[2];
            float vm = fmaxf(v0, fmaxf(v1, v2));
            float e0 = __expf(v0 - vm), e1 = __expf(v1 - vm), e2 = __expf(v2 - vm);
            float inv = 1.0f / (e0 + e1 + e2);
            sh_vw[0] = e0 * inv; sh_vw[1] = e1 * inv; sh_vw[2] = e2 * inv;
        }
    }
    __syncthreads();
    if (tid < 24) {
        int b = tid / 3, c = tid % 3;
        float mean = sh_mw[0] * sh_mean[tid] + sh_mw[1] * sh_mln[b] + sh_mw[2] * sh_mbn[c];
        float var  = sh_vw[0] * sh_var[tid]  + sh_vw[1] * sh_vln[b] + sh_vw[2] * sh_vbn[c];
        float inv = 1.0f / sqrtf(var + EPSn);
        float sc = inv * snw[c];
        float sf = snb[c] - mean * sc;
        sh_scale[tid] = sc; sh_shift[tid] = sf;
        scale[tid] = sc; shift[tid] = sf;
    }
    __syncthreads();
    __shared__ float kvt0[Bn * Cn * Tn], kvt1[Bn * Cn * Tn];
    for (int i = tid; i < Bn * Cn * Tn; i += 256) {
        int bc = i >> 5;
        float4 p = tsum[i];
        kvt0[i] = sh_scale[bc] * p.z + sh_shift[bc] * sWt0;
        kvt1[i] = sh_scale[bc] * p.w + sh_shift[bc] * sWt1;
    }
    __syncthreads();
    if (tid < 24) {
        float m = -3.4e38f;
        for (int t = 0; t < Tn; ++t) m = fmaxf(m, kvt0[tid * Tn + t]);
        float se = 0.f;
        for (int t = 0; t < Tn; ++t) se += __expf(kvt0[tid * Tn + t] - m);
        float inv = 1.0f / se;
        for (int t = 0; t < Tn; ++t)
            A[tid * Tn + t] = sqrtf(__expf(kvt0[tid * Tn + t] - m) * inv) * kvt1[tid * Tn + t];
    }
}

// ------- K5: affine fixup + softmax over s (per bc row) -> B[s] = sqrt(ks)*vs -------
__global__ __launch_bounds__(256) void k5_softmax_s(
    const float* __restrict__ raw0, const float* __restrict__ raw1,
    const float* __restrict__ scale, const float* __restrict__ shift,
    const float* __restrict__ wsum, float* __restrict__ Bv)
{
    const int bc = blockIdx.x;
    const int tid = threadIdx.x;
    const float sc = scale[bc], sf = shift[bc];
    const float c0 = sf * wsum[2], c1 = sf * wsum[3];
    const float* p0 = raw0 + (size_t)bc * HWn;
    const float* p1 = raw1 + (size_t)bc * HWn;
    float* bp = Bv + (size_t)bc * HWn;
    __shared__ float red[256];
    float m = -3.4e38f;
    for (int i = tid * 4; i < HWn; i += 1024) {
        float4 v = *(const float4*)(p0 + i);
        m = fmaxf(m, fmaxf(fmaxf(sc * v.x + c0, sc * v.y + c0),
                           fmaxf(sc * v.z + c0, sc * v.w + c0)));
    }
    red[tid] = m;
    __syncthreads();
    for (int off = 128; off > 0; off >>= 1) {
        if (tid < off) red[tid] = fmaxf(red[tid], red[tid + off]);
        __syncthreads();
    }
    __shared__ float smax, ssum;
    if (tid == 0) smax = red[0];
    __syncthreads();
    const float mx = smax;
    float se = 0.f;
    for (int i = tid * 4; i < HWn; i += 1024) {
        float4 v = *(const float4*)(p0 + i);
        se += __expf(sc * v.x + c0 - mx) + __expf(sc * v.y + c0 - mx) +
              __expf(sc * v.z + c0 - mx) + __expf(sc * v.w + c0 - mx);
    }
    __syncthreads();
    red[tid] = se;
    __syncthreads();
    for (int off = 128; off > 0; off >>= 1) {
        if (tid < off) red[tid] += red[tid + off];
        __syncthreads();
    }
    if (tid == 0) ssum = red[0];
    __syncthreads();
    const float inv = 1.0f / ssum;
    for (int i = tid * 4; i < HWn; i += 1024) {
        float4 v0 = *(const float4*)(p0 + i);
        float4 v1 = *(const float4*)(p1 + i);
        float4 o;
        o.x = sqrtf(__expf(sc * v0.x + c0 - mx) * inv) * (sc * v1.x + c1);
        o.y = sqrtf(__expf(sc * v0.y + c0 - mx) * inv) * (sc * v1.y + c1);
        o.z = sqrtf(__expf(sc * v0.z + c0 - mx) * inv) * (sc * v1.z + c1);
        o.w = sqrtf(__expf(sc * v0.w + c0 - mx) * inv) * (sc * v1.w + c1);
        *(float4*)(bp + i) = o;
    }
}

// ------------- K6: out[bc,t,s] = A[bc,t] * B[bc,s] -------------
__global__ __launch_bounds__(256) void k6_outer(
    const float* __restrict__ A, const float* __restrict__ Bv, float* __restrict__ out)
{
    const int bc = blockIdx.y;       // 24
    const int chunk = blockIdx.x;    // 16 chunks of 1024
    const int tid = threadIdx.x;
    __shared__ float a[Tn];
    if (tid < Tn) a[tid] = A[bc * Tn + tid];
    __syncthreads();
    const int s = chunk * 1024 + tid * 4;
    float4 b4 = *(const float4*)(Bv + (size_t)bc * HWn + s);
    float* op = out + (size_t)bc * Tn * HWn + s;
#pragma unroll
    for (int t = 0; t < Tn; ++t) {
        float av = a[t];
        float4 o;
        o.x = av * b4.x; o.y = av * b4.y; o.z = av * b4.z; o.w = av * b4.w;
        *(float4*)(op + (size_t)t * HWn) = o;
    }
}

extern "C" void kernel_launch(void* const* d_in, const int* in_sizes, int n_in,
                              void* d_out, int out_size, void* d_ws, size_t ws_size,
                              hipStream_t stream) {
    const float* x          = (const float*)d_in[0];
    const float* w_spatial  = (const float*)d_in[1];
    const float* b_spatial  = (const float*)d_in[2];
    const float* w_temporal = (const float*)d_in[3];
    const float* b_temporal = (const float*)d_in[4];
    const float* sn_weight  = (const float*)d_in[5];
    const float* sn_bias    = (const float*)d_in[6];
    const float* mean_weight= (const float*)d_in[7];
    const float* var_weight = (const float*)d_in[8];
    const float* w_kv_s     = (const float*)d_in[9];
    const float* w_kv_t     = (const float*)d_in[10];
    float* out = (float*)d_out;
    float* ws  = (float*)d_ws;

    // ws: y occupies [0, 12.58M); after k2, y is dead and its region is reused:
    //   Bv @ ws[0..393216), scale/shift/A/wsum right after.
    float* y     = ws;
    float* Bv    = ws;
    float* scale = ws + (size_t)Bn * Cn * HWn;       // 393216
    float* shift = scale + 24;
    float* A     = shift + 24;
    float* wsum  = A + Bn * Cn * Tn;
    // d_out doubles as scratch until k6 overwrites it:
    float*  raw0     = out;                                   // 393216 floats
    float*  raw1     = out + (size_t)Bn * Cn * HWn;           // 393216 floats
    float4* partials = (float4*)(out + 2 * (size_t)Bn * Cn * HWn);  // 12288 float4

    k1_spatial<<<dim3(Bn * Tn, Hn / 16), 256, 0, stream>>>(x, w_spatial, b_spatial, y);
    k2_temporal<<<dim3(NCHUNK, Bn * Cn), 256, 0, stream>>>(y, w_temporal, b_temporal,
                                                           w_kv_t, w_kv_s,
                                                           raw0, raw1, partials);
    k3_finalize<<<1, 256, 0, stream>>>(partials, mean_weight, var_weight, sn_weight,
                                       sn_bias, w_kv_t, w_kv_s, scale, shift, A, wsum);
    k5_softmax_s<<<Bn * Cn, 256, 0, stream>>>(raw0, raw1, scale, shift, wsum, Bv);
    k6_outer<<<dim3(NCHUNK, Bn * Cn), 256, 0, stream>>>(A, Bv, out);
}

// Round 3
// 99.613 us; speedup vs baseline: 1.6157x; 1.0977x over previous
//
#include <hip/hip_runtime.h>
#include <hip/hip_bf16.h>

#define Bn 8
#define Cn 3
#define Tn 32
#define Hn 128
#define Wn 128
#define HWn (Hn * Wn)          // 16384
#define Nn (Tn * HWn)          // 524288 elems per (b,c)
#define EPSn 1e-5f
#define NCH 32                 // 32 h-tiles (chunks) of 512 pixels each

__device__ __forceinline__ float silu_f(float v) {
    return v / (1.0f + __expf(-v));
}

// ========== K12: fused spatial 3x3 conv + temporal 7-tap conv + all analytics ==========
// Block = (ht, b): 4 rows x 128 cols tile of one b; 256 threads; thread owns 2 px.
// Streams t: x slice (6 rows incl. halo) staged in LDS (double-buffered, 2-deep
// register prefetch); y kept in a 7-deep register ring (3 ch x float2). Produces:
//   raw0/raw1[bc][s]  = sum_t wks{0,1}[t] * g[t,s]          (kv_s contraction)
//   pt0p/pt1p[bc][t][ht] = partial sum_s g[t,s]*wkt{0,1}[s] (kv_t contraction)
//   ss0p/ss1p[bc][ht]    = partial {sum g, sum g^2}         (SwitchNorm stats)
// g itself is never written (final output is rank-1 per (b,c): A[t]*B[s]).
__global__ __launch_bounds__(256) void k12_conv(
    const float* __restrict__ x, const float* __restrict__ wsp,
    const float* __restrict__ bsp, const float* __restrict__ wtp,
    const float* __restrict__ btp, const float* __restrict__ wkt,
    const float* __restrict__ wks,
    float* __restrict__ raw0, float* __restrict__ raw1,
    float* __restrict__ pt0p, float* __restrict__ pt1p,
    float* __restrict__ ss0p, float* __restrict__ ss1p)
{
    const int ht = blockIdx.x;          // 0..31
    const int b  = blockIdx.y;          // 0..7
    const int h0 = ht * 4;
    const int tid = threadIdx.x;
    const int lane = tid & 63;
    const int wave = tid >> 6;
    const int prow = wave;              // tile row 0..3
    const int pcol = lane * 2;          // tile col 0..126 (2 px/thread)

    __shared__ float xs[2][6][130];     // x slice, col shifted +1 (halo), 6.1 KB
    __shared__ float wred[Tn][6][33];   // per-t pt partials (8-lane groups), 25.3 KB
    __shared__ float w0s[Tn], w1s[Tn];
    __shared__ float redf[6][4];

    for (int i = tid; i < 2 * 6 * 130; i += 256) ((float*)xs)[i] = 0.f;
    if (tid < Tn) { w0s[tid] = wks[tid]; w1s[tid] = wks[Tn + tid]; }

    // uniform weights (compiler -> scalar regs)
    float wsp_r[27], bsp_r[3], wt_r[21], bt_r[3];
#pragma unroll
    for (int i = 0; i < 27; ++i) wsp_r[i] = wsp[i];
#pragma unroll
    for (int i = 0; i < 3; ++i) bsp_r[i] = bsp[i];
#pragma unroll
    for (int i = 0; i < 21; ++i) wt_r[i] = wtp[i];
#pragma unroll
    for (int i = 0; i < 3; ++i) bt_r[i] = btp[i];

    // x-slice loader mapping: 192 threads load one float4 each
    const bool ldact = tid < 192;
    const int ldr = tid >> 5;                 // 0..5 (row in slice)
    const int ldc = (tid & 31) * 4;           // col 0..124
    const int gh = h0 - 1 + ldr;
    const bool ghok = ldact && (gh >= 0) && (gh < Hn);
    const float* xbase = x + ((size_t)b * Tn) * HWn + (size_t)(gh < 0 ? 0 : gh) * Wn + ldc;

    // wkt values at this thread's 2 pixels
    const int spix = ht * 512 + tid * 2;
    const float2 k0v = *(const float2*)(wkt + spix);
    const float2 k1v = *(const float2*)(wkt + HWn + spix);

    float2 ring[7][3];
    float2 a0[3], a1[3];
    float ps[3], pq[3];
#pragma unroll
    for (int c = 0; c < 3; ++c) {
        a0[c].x = 0.f; a0[c].y = 0.f; a1[c].x = 0.f; a1[c].y = 0.f;
        ps[c] = 0.f; pq[c] = 0.f;
    }

#define LDSLICE(t) (ghok ? *(const float4*)(xbase + (size_t)(t) * HWn) : (float4){0.f,0.f,0.f,0.f})
#define WRSLICE(buf, v) do { if (ghok) { \
        xs[buf][ldr][1+ldc+0] = (v).x; xs[buf][ldr][1+ldc+1] = (v).y; \
        xs[buf][ldr][1+ldc+2] = (v).z; xs[buf][ldr][1+ldc+3] = (v).w; } } while (0)

    // prologue: slice0 -> xs[0], slice1/2 in flight
    float4 sA = LDSLICE(0);
    WRSLICE(0, sA);
    float4 sB = LDSLICE(1);
    sA = LDSLICE(2);
    __syncthreads();

#pragma unroll
    for (int tt = 0; tt < Tn + 3; ++tt) {
        const int cur = tt & 1, nxt = cur ^ 1;
        // stage slice tt+1 into LDS, refill its register with slice tt+3
        if (tt + 1 < Tn) {
            if ((tt + 1) & 1) {
                WRSLICE(nxt, sB);
                if (tt + 3 < Tn) sB = LDSLICE(tt + 3);
            } else {
                WRSLICE(nxt, sA);
                if (tt + 3 < Tn) sA = LDSLICE(tt + 3);
            }
        }
        // spatial conv for slice tt
        if (tt < Tn) {
            float xv[3][4];
#pragma unroll
            for (int dr = 0; dr < 3; ++dr) {
                float2 p01 = *(const float2*)&xs[cur][prow + dr][pcol + 0];
                float2 p23 = *(const float2*)&xs[cur][prow + dr][pcol + 2];
                xv[dr][0] = p01.x; xv[dr][1] = p01.y; xv[dr][2] = p23.x; xv[dr][3] = p23.y;
            }
#pragma unroll
            for (int c = 0; c < 3; ++c) {
                float s0 = bsp_r[c], s1 = bsp_r[c];
#pragma unroll
                for (int i = 0; i < 3; ++i) {
#pragma unroll
                    for (int j = 0; j < 3; ++j) {
                        const float wv = wsp_r[c * 9 + i * 3 + j];
                        s0 += wv * xv[i][j];
                        s1 += wv * xv[i][j + 1];
                    }
                }
                ring[tt % 7][c].x = silu_f(s0);
                ring[tt % 7][c].y = silu_f(s1);
            }
        }
        // temporal conv + analytics for to = tt-3
        if (tt >= 3) {
            const int to = tt - 3;
            float g[3][2];
            const float wk0 = w0s[to], wk1 = w1s[to];
#pragma unroll
            for (int c = 0; c < 3; ++c) {
                float t0 = bt_r[c], t1 = bt_r[c];
#pragma unroll
                for (int k = 0; k < 7; ++k) {
                    const int ts = to + k - 3;
                    if (ts >= 0 && ts < Tn) {       // resolves at compile time
                        const float wv = wt_r[c * 7 + k];
                        t0 += wv * ring[ts % 7][c].x;
                        t1 += wv * ring[ts % 7][c].y;
                    }
                }
                t0 = silu_f(silu_f(t0)); t1 = silu_f(silu_f(t1));
                g[c][0] = t0; g[c][1] = t1;
                a0[c].x += wk0 * t0; a0[c].y += wk0 * t1;
                a1[c].x += wk1 * t0; a1[c].y += wk1 * t1;
                ps[c] += t0 + t1;
                pq[c] += t0 * t0 + t1 * t1;
            }
            float pv[6];
#pragma unroll
            for (int c = 0; c < 3; ++c) {
                pv[c * 2 + 0] = k0v.x * g[c][0] + k0v.y * g[c][1];
                pv[c * 2 + 1] = k1v.x * g[c][0] + k1v.y * g[c][1];
            }
#pragma unroll
            for (int v = 0; v < 6; ++v) {
                pv[v] += __shfl_xor(pv[v], 1, 64);
                pv[v] += __shfl_xor(pv[v], 2, 64);
                pv[v] += __shfl_xor(pv[v], 4, 64);
            }
            const int j = lane & 7;       // after 3-stage xor, all lanes hold 8-group sum
            if (j < 6) {
                const float val = (j == 0) ? pv[0] : (j == 1) ? pv[1] : (j == 2) ? pv[2]
                                : (j == 3) ? pv[3] : (j == 4) ? pv[4] : pv[5];
                wred[to][j][(wave << 3) | (lane >> 3)] = val;
            }
        }
        __syncthreads();
    }
#undef LDSLICE
#undef WRSLICE

    // --- block-reduce ps/pq (sum g, sum g^2) ---
    float sv[6] = { ps[0], ps[1], ps[2], pq[0], pq[1], pq[2] };
#pragma unroll
    for (int v = 0; v < 6; ++v) {
#pragma unroll
        for (int d = 1; d < 64; d <<= 1) sv[v] += __shfl_xor(sv[v], d, 64);
    }
    if (lane == 0) {
#pragma unroll
        for (int v = 0; v < 6; ++v) redf[v][wave] = sv[v];
    }
    __syncthreads();
    if (tid < 3) {
        ss0p[(size_t)(b * 3 + tid) * NCH + ht] =
            redf[tid][0] + redf[tid][1] + redf[tid][2] + redf[tid][3];
    } else if (tid < 6) {
        ss1p[(size_t)(b * 3 + tid - 3) * NCH + ht] =
            redf[tid][0] + redf[tid][1] + redf[tid][2] + redf[tid][3];
    }
    // --- reduce wred -> pt partials ---
    if (tid < 192) {
        const int t = tid / 6, cv = tid % 6;
        float s = 0.f;
#pragma unroll
        for (int i = 0; i < 32; ++i) s += wred[t][cv][i];
        const int c = cv >> 1, v = cv & 1;
        float* dst = v ? pt1p : pt0p;
        dst[((size_t)(b * 3 + c) * Tn + t) * NCH + ht] = s;
    }
    // --- raw kv_s stores ---
#pragma unroll
    for (int c = 0; c < 3; ++c) {
        const size_t off = (size_t)(b * 3 + c) * HWn + spix;
        *(float2*)(raw0 + off) = a0[c];
        *(float2*)(raw1 + off) = a1[c];
    }
}

// ========== K3: reduce partials + SwitchNorm stats + kv_t softmax -> A, scale/shift ==========
__global__ __launch_bounds__(256) void k3_finalize(
    const float* __restrict__ pt0p, const float* __restrict__ pt1p,
    const float* __restrict__ ss0p, const float* __restrict__ ss1p,
    const float* __restrict__ mean_w, const float* __restrict__ var_w,
    const float* __restrict__ snw, const float* __restrict__ snb,
    const float* __restrict__ wkt, const float* __restrict__ wks,
    float* __restrict__ scale, float* __restrict__ shift,
    float* __restrict__ A, float* __restrict__ wsum)
{
    const int tid = threadIdx.x;
    __shared__ float kvt0[Bn * Cn * Tn], kvt1[Bn * Cn * Tn];
    for (int i = tid; i < Bn * Cn * Tn; i += 256) {
        const float* p0 = pt0p + (size_t)i * NCH;
        const float* p1 = pt1p + (size_t)i * NCH;
        float s0 = 0.f, s1 = 0.f;
        for (int j = 0; j < NCH; ++j) { s0 += p0[j]; s1 += p1[j]; }
        kvt0[i] = s0; kvt1[i] = s1;
    }
    __shared__ float red0[256], red1[256];
    float l0 = 0.f, l1 = 0.f;
    for (int i = tid; i < HWn; i += 256) { l0 += wkt[i]; l1 += wkt[HWn + i]; }
    red0[tid] = l0; red1[tid] = l1;
    __syncthreads();
    for (int off = 128; off > 0; off >>= 1) {
        if (tid < off) { red0[tid] += red0[tid + off]; red1[tid] += red1[tid + off]; }
        __syncthreads();
    }
    __shared__ float sWt0, sWt1;
    __shared__ float sh_mean[24], sh_var[24], sh_temp[24];
    __shared__ float sh_mln[8], sh_vln[8], sh_mbn[3], sh_vbn[3];
    __shared__ float sh_mw[3], sh_vw[3];
    __shared__ float sh_scale[24], sh_shift[24];
    if (tid == 0) {
        sWt0 = red0[0]; sWt1 = red1[0];
        float a = 0.f, bb = 0.f;
        for (int t = 0; t < Tn; ++t) { a += wks[t]; bb += wks[Tn + t]; }
        wsum[0] = sWt0; wsum[1] = sWt1; wsum[2] = a; wsum[3] = bb;
    }
    if (tid < 24) {
        float S = 0.f, SS = 0.f;
        for (int j = 0; j < NCH; ++j) {
            S += ss0p[(size_t)tid * NCH + j];
            SS += ss1p[(size_t)tid * NCH + j];
        }
        const float Nf = (float)Nn;
        float mean = S / Nf;
        float var = (SS - S * mean) / (Nf - 1.0f);   // unbiased (ddof=1)
        sh_mean[tid] = mean; sh_var[tid] = var; sh_temp[tid] = var + mean * mean;
    }
    __syncthreads();
    if (tid == 0) {
        for (int b = 0; b < Bn; ++b) {
            float m = 0.f, tp = 0.f;
            for (int c = 0; c < Cn; ++c) { m += sh_mean[b * 3 + c]; tp += sh_temp[b * 3 + c]; }
            m *= (1.0f / 3.0f); tp *= (1.0f / 3.0f);
            sh_mln[b] = m; sh_vln[b] = tp - m * m;
        }
        for (int c = 0; c < Cn; ++c) {
            float m = 0.f, tp = 0.f;
            for (int b = 0; b < Bn; ++b) { m += sh_mean[b * 3 + c]; tp += sh_temp[b * 3 + c]; }
            m *= 0.125f; tp *= 0.125f;
            sh_mbn[c] = m; sh_vbn[c] = tp - m * m;
        }
        {
            float m0 = mean_w[0], m1 = mean_w[1], m2 = mean_w[2];
            float mm = fmaxf(m0, fmaxf(m1, m2));
            float e0 = __expf(m0 - mm), e1 = __expf(m1 - mm), e2 = __expf(m2 - mm);
            float inv = 1.0f / (e0 + e1 + e2);
            sh_mw[0] = e0 * inv; sh_mw[1] = e1 * inv; sh_mw[2] = e2 * inv;
        }
        {
            float v0 = var_w[0], v1 = var_w[1], v2 = var_w[2];
            float vm = fmaxf(v0, fmaxf(v1, v2));
            float e0 = __expf(v0 - vm), e1 = __expf(v1 - vm), e2 = __expf(v2 - vm);
            float inv = 1.0f / (e0 + e1 + e2);
            sh_vw[0] = e0 * inv; sh_vw[1] = e1 * inv; sh_vw[2] = e2 * inv;
        }
    }
    __syncthreads();
    if (tid < 24) {
        int b = tid / 3, c = tid % 3;
        float mean = sh_mw[0] * sh_mean[tid] + sh_mw[1] * sh_mln[b] + sh_mw[2] * sh_mbn[c];
        float var  = sh_vw[0] * sh_var[tid]  + sh_vw[1] * sh_vln[b] + sh_vw[2] * sh_vbn[c];
        float inv = 1.0f / sqrtf(var + EPSn);
        float sc = inv * snw[c];
        float sf = snb[c] - mean * sc;
        sh_scale[tid] = sc; sh_shift[tid] = sf;
        scale[tid] = sc; shift[tid] = sf;
    }
    __syncthreads();
    for (int i = tid; i < Bn * Cn * Tn; i += 256) {
        int bc = i >> 5;
        kvt0[i] = sh_scale[bc] * kvt0[i] + sh_shift[bc] * sWt0;
        kvt1[i] = sh_scale[bc] * kvt1[i] + sh_shift[bc] * sWt1;
    }
    __syncthreads();
    if (tid < 24) {
        float m = -3.4e38f;
        for (int t = 0; t < Tn; ++t) m = fmaxf(m, kvt0[tid * Tn + t]);
        float se = 0.f;
        for (int t = 0; t < Tn; ++t) se += __expf(kvt0[tid * Tn + t] - m);
        float inv = 1.0f / se;
        for (int t = 0; t < Tn; ++t)
            A[tid * Tn + t] = sqrtf(__expf(kvt0[tid * Tn + t] - m) * inv) * kvt1[tid * Tn + t];
    }
}

// ========== K5a: per-chunk max/expsum of the s-softmax input ==========
__global__ __launch_bounds__(256) void k5a_maxsum(
    const float* __restrict__ raw0, const float* __restrict__ scale,
    const float* __restrict__ shift, const float* __restrict__ wsum,
    float2* __restrict__ ms)
{
    const int ch = blockIdx.x;   // 0..7 (chunks of 2048)
    const int bc = blockIdx.y;   // 0..23
    const int tid = threadIdx.x, lane = tid & 63, wave = tid >> 6;
    const float sc = scale[bc], c0 = shift[bc] * wsum[2];
    const float* p = raw0 + (size_t)bc * HWn + ch * 2048 + tid * 8;
    float4 v0 = ((const float4*)p)[0], v1 = ((const float4*)p)[1];
    float vals[8] = { v0.x, v0.y, v0.z, v0.w, v1.x, v1.y, v1.z, v1.w };
    float m = -3.4e38f;
#pragma unroll
    for (int i = 0; i < 8; ++i) m = fmaxf(m, sc * vals[i] + c0);
#pragma unroll
    for (int d = 1; d < 64; d <<= 1) m = fmaxf(m, __shfl_xor(m, d, 64));
    __shared__ float wm[4], wsm[4];
    if (lane == 0) wm[wave] = m;
    __syncthreads();
    const float M = fmaxf(fmaxf(wm[0], wm[1]), fmaxf(wm[2], wm[3]));
    float s = 0.f;
#pragma unroll
    for (int i = 0; i < 8; ++i) s += __expf(sc * vals[i] + c0 - M);
#pragma unroll
    for (int d = 1; d < 64; d <<= 1) s += __shfl_xor(s, d, 64);
    if (lane == 0) wsm[wave] = s;
    __syncthreads();
    if (tid == 0) {
        float2 o; o.x = M; o.y = wsm[0] + wsm[1] + wsm[2] + wsm[3];
        ms[bc * 8 + ch] = o;
    }
}

// ========== K6: B finalize inline + outer product out[bc,t,s] = A[t]*B[s] ==========
__global__ __launch_bounds__(256) void k6_outer(
    const float* __restrict__ raw0, const float* __restrict__ raw1,
    const float* __restrict__ scale, const float* __restrict__ shift,
    const float* __restrict__ wsum, const float2* __restrict__ ms,
    const float* __restrict__ A, float* __restrict__ out)
{
    const int ch = blockIdx.x;   // 0..15 (chunks of 1024)
    const int bc = blockIdx.y;   // 0..23
    const int tid = threadIdx.x;
    __shared__ float a[Tn];
    if (tid < Tn) a[tid] = A[bc * Tn + tid];
    const float sc = scale[bc], sf = shift[bc];
    const float c0 = sf * wsum[2], c1 = sf * wsum[3];
    float M = -3.4e38f;
#pragma unroll
    for (int j = 0; j < 8; ++j) M = fmaxf(M, ms[bc * 8 + j].x);
    float S = 0.f;
#pragma unroll
    for (int j = 0; j < 8; ++j) S += ms[bc * 8 + j].y * __expf(ms[bc * 8 + j].x - M);
    const float invS = 1.0f / S;
    const int s = ch * 1024 + tid * 4;
    float4 r0 = *(const float4*)(raw0 + (size_t)bc * HWn + s);
    float4 r1 = *(const float4*)(raw1 + (size_t)bc * HWn + s);
    float4 Bv;
    Bv.x = sqrtf(__expf(sc * r0.x + c0 - M) * invS) * (sc * r1.x + c1);
    Bv.y = sqrtf(__expf(sc * r0.y + c0 - M) * invS) * (sc * r1.y + c1);
    Bv.z = sqrtf(__expf(sc * r0.z + c0 - M) * invS) * (sc * r1.z + c1);
    Bv.w = sqrtf(__expf(sc * r0.w + c0 - M) * invS) * (sc * r1.w + c1);
    __syncthreads();
    float* op = out + (size_t)bc * Nn + s;
#pragma unroll
    for (int t = 0; t < Tn; ++t) {
        const float av = a[t];
        float4 o; o.x = av * Bv.x; o.y = av * Bv.y; o.z = av * Bv.z; o.w = av * Bv.w;
        *(float4*)(op + (size_t)t * HWn) = o;
    }
}

extern "C" void kernel_launch(void* const* d_in, const int* in_sizes, int n_in,
                              void* d_out, int out_size, void* d_ws, size_t ws_size,
                              hipStream_t stream) {
    const float* x          = (const float*)d_in[0];
    const float* w_spatial  = (const float*)d_in[1];
    const float* b_spatial  = (const float*)d_in[2];
    const float* w_temporal = (const float*)d_in[3];
    const float* b_temporal = (const float*)d_in[4];
    const float* sn_weight  = (const float*)d_in[5];
    const float* sn_bias    = (const float*)d_in[6];
    const float* mean_weight= (const float*)d_in[7];
    const float* var_weight = (const float*)d_in[8];
    const float* w_kv_s     = (const float*)d_in[9];
    const float* w_kv_t     = (const float*)d_in[10];
    float* out = (float*)d_out;
    float* ws  = (float*)d_ws;

    // ws layout (floats) — everything lives in d_ws, d_out written only by k6
    float* raw0  = ws;                         // 393216
    float* raw1  = raw0 + (size_t)Bn * Cn * HWn;       // 393216
    float* pt0p  = raw1 + (size_t)Bn * Cn * HWn;       // 24576
    float* pt1p  = pt0p + (size_t)Bn * Cn * Tn * NCH;  // 24576
    float* ss0p  = pt1p + (size_t)Bn * Cn * Tn * NCH;  // 768
    float* ss1p  = ss0p + (size_t)Bn * Cn * NCH;       // 768
    float* scale = ss1p + (size_t)Bn * Cn * NCH;       // 24
    float* shift = scale + 24;                         // 24
    float* A     = shift + 24;                         // 768
    float* wsum  = A + Bn * Cn * Tn;                   // 4
    float2* ms   = (float2*)(wsum + 4);                // 192 float2

    k12_conv<<<dim3(NCH, Bn), 256, 0, stream>>>(x, w_spatial, b_spatial,
                                                w_temporal, b_temporal,
                                                w_kv_t, w_kv_s,
                                                raw0, raw1, pt0p, pt1p, ss0p, ss1p);
    k3_finalize<<<1, 256, 0, stream>>>(pt0p, pt1p, ss0p, ss1p,
                                       mean_weight, var_weight, sn_weight, sn_bias,
                                       w_kv_t, w_kv_s, scale, shift, A, wsum);
    k5a_maxsum<<<dim3(8, Bn * Cn), 256, 0, stream>>>(raw0, scale, shift, wsum, ms);
    k6_outer<<<dim3(16, Bn * Cn), 256, 0, stream>>>(raw0, raw1, scale, shift, wsum,
                                                    ms, A, out);
}

// Round 4
// 88.489 us; speedup vs baseline: 1.8188x; 1.1257x over previous
//
#include <hip/hip_runtime.h>
#include <hip/hip_bf16.h>

#define Bn 8
#define Cn 3
#define Tn 32
#define Hn 128
#define Wn 128
#define HWn (Hn * Wn)          // 16384
#define Nn (Tn * HWn)          // 524288 elems per (b,c)
#define EPSn 1e-5f
#define RTn 32                 // 32 row-tiles (4 rows each)

__device__ __forceinline__ float silu_f(float v) {
    return v / (1.0f + __expf(-v));
}

// ========== K12: fused spatial 3x3 conv + temporal 7-tap conv + all analytics ==========
// Block = (rt, b, half): 4 rows x 128 cols, 256 threads = 4 waves; wave = one row,
// thread = 2 px. No LDS for x: vertical halo via direct loads of rows h-1/h/h+1
// (L1/L2-hot), horizontal halo via __shfl_up/down. t streamed with a 7-deep register
// ring (3 ch x float2); t split in 2 halves (3-slice halo) for 512-block parallelism.
// No per-t __syncthreads. Outputs:
//   raw0/raw1[half][bc][s]   = partial sum_t wks{0,1}[t]*g      (kv_s contraction)
//   pt0p/pt1p[bc][t][rt]     = partial sum_s g*wkt{0,1}[s]      (kv_t contraction)
//   ss0p/ss1p[bc][rt*2+half] = partial {sum g, sum g^2}         (SwitchNorm stats)
template<int HALF>
__device__ __forceinline__ void k12_body(
    const float* __restrict__ x, const float* __restrict__ wsp,
    const float* __restrict__ bsp, const float* __restrict__ wtp,
    const float* __restrict__ btp, const float* __restrict__ wkt,
    const float* __restrict__ wks,
    float* __restrict__ raw0, float* __restrict__ raw1,
    float* __restrict__ pt0p, float* __restrict__ pt1p,
    float* __restrict__ ss0p, float* __restrict__ ss1p)
{
    constexpr int O0 = HALF * 16;
    constexpr int O1 = O0 + 16;
    constexpr int SLO = (O0 - 3 < 0) ? 0 : (O0 - 3);
    constexpr int SHI = (O1 + 2 > Tn - 1) ? (Tn - 1) : (O1 + 2);

    const int rt = blockIdx.x;          // 0..31
    const int b  = blockIdx.y;          // 0..7
    const int tid = threadIdx.x, lane = tid & 63, wave = tid >> 6;
    const int h = rt * 4 + wave;        // global row, wave owns it
    const int col = lane * 2;

    __shared__ float wred[16][6][33];   // per-t kv_t partials (8-lane groups), 12.7 KB
    __shared__ float redf[6][4];

    // uniform weights -> scalar regs
    float wsp_r[27], bsp_r[3], wt_r[21], bt_r[3];
#pragma unroll
    for (int i = 0; i < 27; ++i) wsp_r[i] = wsp[i];
#pragma unroll
    for (int i = 0; i < 3; ++i) bsp_r[i] = bsp[i];
#pragma unroll
    for (int i = 0; i < 21; ++i) wt_r[i] = wtp[i];
#pragma unroll
    for (int i = 0; i < 3; ++i) bt_r[i] = btp[i];

    const float* xb = x + (size_t)b * Nn + (size_t)h * Wn + col;
    const bool upok = h > 0, dnok = h < Hn - 1;

    const float2 k0v = *(const float2*)(wkt + h * Wn + col);
    const float2 k1v = *(const float2*)(wkt + HWn + h * Wn + col);

    float2 ring[7][3];
    float2 a0[3], a1[3];
    float ps[3], pq[3];
#pragma unroll
    for (int c = 0; c < 3; ++c) {
        a0[c] = make_float2(0.f, 0.f); a1[c] = make_float2(0.f, 0.f);
        ps[c] = 0.f; pq[c] = 0.f;
    }

#pragma unroll
    for (int tt = SLO; tt <= SHI + 3; ++tt) {
        if (tt <= SHI) {
            const float* xsl = xb + (size_t)tt * HWn;
            float2 xm = upok ? *(const float2*)(xsl - Wn) : make_float2(0.f, 0.f);
            float2 xc = *(const float2*)(xsl);
            float2 xp = dnok ? *(const float2*)(xsl + Wn) : make_float2(0.f, 0.f);
            float xv[3][4];
            {
                float lu, rd;
                lu = __shfl_up(xm.y, 1);  rd = __shfl_down(xm.x, 1);
                xv[0][0] = (lane == 0) ? 0.f : lu; xv[0][1] = xm.x; xv[0][2] = xm.y;
                xv[0][3] = (lane == 63) ? 0.f : rd;
                lu = __shfl_up(xc.y, 1);  rd = __shfl_down(xc.x, 1);
                xv[1][0] = (lane == 0) ? 0.f : lu; xv[1][1] = xc.x; xv[1][2] = xc.y;
                xv[1][3] = (lane == 63) ? 0.f : rd;
                lu = __shfl_up(xp.y, 1);  rd = __shfl_down(xp.x, 1);
                xv[2][0] = (lane == 0) ? 0.f : lu; xv[2][1] = xp.x; xv[2][2] = xp.y;
                xv[2][3] = (lane == 63) ? 0.f : rd;
            }
#pragma unroll
            for (int c = 0; c < 3; ++c) {
                float s0 = bsp_r[c], s1 = bsp_r[c];
#pragma unroll
                for (int i = 0; i < 3; ++i) {
#pragma unroll
                    for (int j = 0; j < 3; ++j) {
                        const float wv = wsp_r[c * 9 + i * 3 + j];
                        s0 += wv * xv[i][j];
                        s1 += wv * xv[i][j + 1];
                    }
                }
                ring[tt % 7][c].x = silu_f(s0);
                ring[tt % 7][c].y = silu_f(s1);
            }
        }
        const int to = tt - 3;
        if (to >= O0 && to < O1) {          // compile-time pruned per unrolled iter
            float g0[3], g1[3];
            const float wk0 = wks[to];      // uniform scalar loads
            const float wk1 = wks[Tn + to];
#pragma unroll
            for (int c = 0; c < 3; ++c) {
                float t0 = bt_r[c], t1 = bt_r[c];
#pragma unroll
                for (int k = 0; k < 7; ++k) {
                    const int ts = to + k - 3;
                    if (ts >= 0 && ts < Tn) {   // compile-time
                        const float wv = wt_r[c * 7 + k];
                        t0 += wv * ring[ts % 7][c].x;
                        t1 += wv * ring[ts % 7][c].y;
                    }
                }
                t0 = silu_f(silu_f(t0)); t1 = silu_f(silu_f(t1));
                g0[c] = t0; g1[c] = t1;
                a0[c].x += wk0 * t0; a0[c].y += wk0 * t1;
                a1[c].x += wk1 * t0; a1[c].y += wk1 * t1;
                ps[c] += t0 + t1;
                pq[c] += t0 * t0 + t1 * t1;
            }
            float pv[6];
#pragma unroll
            for (int c = 0; c < 3; ++c) {
                pv[c * 2 + 0] = k0v.x * g0[c] + k0v.y * g1[c];
                pv[c * 2 + 1] = k1v.x * g0[c] + k1v.y * g1[c];
            }
#pragma unroll
            for (int v = 0; v < 6; ++v) {
                pv[v] += __shfl_xor(pv[v], 1, 64);
                pv[v] += __shfl_xor(pv[v], 2, 64);
                pv[v] += __shfl_xor(pv[v], 4, 64);
            }
            const int j = lane & 7;
            if (j < 6) {
                const float val = (j == 0) ? pv[0] : (j == 1) ? pv[1] : (j == 2) ? pv[2]
                                : (j == 3) ? pv[3] : (j == 4) ? pv[4] : pv[5];
                wred[to - O0][j][(wave << 3) | (lane >> 3)] = val;
            }
        }
    }

    // --- block-reduce ps/pq ---
    float sv[6] = { ps[0], ps[1], ps[2], pq[0], pq[1], pq[2] };
#pragma unroll
    for (int v = 0; v < 6; ++v) {
#pragma unroll
        for (int d = 1; d < 64; d <<= 1) sv[v] += __shfl_xor(sv[v], d, 64);
    }
    if (lane == 0) {
#pragma unroll
        for (int v = 0; v < 6; ++v) redf[v][wave] = sv[v];
    }
    __syncthreads();
    if (tid < 3) {
        ss0p[(size_t)(b * 3 + tid) * (RTn * 2) + rt * 2 + HALF] =
            redf[tid][0] + redf[tid][1] + redf[tid][2] + redf[tid][3];
    } else if (tid < 6) {
        ss1p[(size_t)(b * 3 + tid - 3) * (RTn * 2) + rt * 2 + HALF] =
            redf[tid][0] + redf[tid][1] + redf[tid][2] + redf[tid][3];
    }
    // --- reduce wred -> pt partials (16 local t x 6 vals) ---
    if (tid < 96) {
        const int t = tid / 6, cv = tid % 6;
        float s = 0.f;
#pragma unroll
        for (int i = 0; i < 32; ++i) s += wred[t][cv][i];
        const int c = cv >> 1, v = cv & 1;
        float* dst = v ? pt1p : pt0p;
        dst[((size_t)(b * 3 + c) * Tn + O0 + t) * RTn + rt] = s;
    }
    // --- raw kv_s stores (per-half buffers) ---
#pragma unroll
    for (int c = 0; c < 3; ++c) {
        const size_t off = (size_t)(HALF * 24 + b * 3 + c) * HWn + (size_t)h * Wn + col;
        *(float2*)(raw0 + off) = a0[c];
        *(float2*)(raw1 + off) = a1[c];
    }
}

__global__ __launch_bounds__(256) void k12_conv(
    const float* __restrict__ x, const float* __restrict__ wsp,
    const float* __restrict__ bsp, const float* __restrict__ wtp,
    const float* __restrict__ btp, const float* __restrict__ wkt,
    const float* __restrict__ wks,
    float* __restrict__ raw0, float* __restrict__ raw1,
    float* __restrict__ pt0p, float* __restrict__ pt1p,
    float* __restrict__ ss0p, float* __restrict__ ss1p)
{
    if (blockIdx.z == 0)
        k12_body<0>(x, wsp, bsp, wtp, btp, wkt, wks, raw0, raw1, pt0p, pt1p, ss0p, ss1p);
    else
        k12_body<1>(x, wsp, bsp, wtp, btp, wkt, wks, raw0, raw1, pt0p, pt1p, ss0p, ss1p);
}

// ========== K3: reduce partials + SwitchNorm stats + kv_t softmax -> A, scale/shift ==========
__global__ __launch_bounds__(256) void k3_finalize(
    const float* __restrict__ pt0p, const float* __restrict__ pt1p,
    const float* __restrict__ ss0p, const float* __restrict__ ss1p,
    const float* __restrict__ mean_w, const float* __restrict__ var_w,
    const float* __restrict__ snw, const float* __restrict__ snb,
    const float* __restrict__ wkt, const float* __restrict__ wks,
    float* __restrict__ scale, float* __restrict__ shift,
    float* __restrict__ A, float* __restrict__ wsum)
{
    const int tid = threadIdx.x;
    __shared__ float kvt0[Bn * Cn * Tn], kvt1[Bn * Cn * Tn];
    for (int i = tid; i < Bn * Cn * Tn; i += 256) {
        const float* p0 = pt0p + (size_t)i * RTn;
        const float* p1 = pt1p + (size_t)i * RTn;
        float s0 = 0.f, s1 = 0.f;
        for (int j = 0; j < RTn; ++j) { s0 += p0[j]; s1 += p1[j]; }
        kvt0[i] = s0; kvt1[i] = s1;
    }
    __shared__ float red0[256], red1[256];
    float l0 = 0.f, l1 = 0.f;
    for (int i = tid; i < HWn; i += 256) { l0 += wkt[i]; l1 += wkt[HWn + i]; }
    red0[tid] = l0; red1[tid] = l1;
    __syncthreads();
    for (int off = 128; off > 0; off >>= 1) {
        if (tid < off) { red0[tid] += red0[tid + off]; red1[tid] += red1[tid + off]; }
        __syncthreads();
    }
    __shared__ float sWt0, sWt1;
    __shared__ float sh_mean[24], sh_var[24], sh_temp[24];
    __shared__ float sh_mln[8], sh_vln[8], sh_mbn[3], sh_vbn[3];
    __shared__ float sh_mw[3], sh_vw[3];
    __shared__ float sh_scale[24], sh_shift[24];
    if (tid == 0) {
        sWt0 = red0[0]; sWt1 = red1[0];
        float a = 0.f, bb = 0.f;
        for (int t = 0; t < Tn; ++t) { a += wks[t]; bb += wks[Tn + t]; }
        wsum[0] = sWt0; wsum[1] = sWt1; wsum[2] = a; wsum[3] = bb;
    }
    if (tid < 24) {
        float S = 0.f, SS = 0.f;
        for (int j = 0; j < RTn * 2; ++j) {
            S += ss0p[(size_t)tid * (RTn * 2) + j];
            SS += ss1p[(size_t)tid * (RTn * 2) + j];
        }
        const float Nf = (float)Nn;
        float mean = S / Nf;
        float var = (SS - S * mean) / (Nf - 1.0f);   // unbiased (ddof=1)
        sh_mean[tid] = mean; sh_var[tid] = var; sh_temp[tid] = var + mean * mean;
    }
    __syncthreads();
    if (tid == 0) {
        for (int b = 0; b < Bn; ++b) {
            float m = 0.f, tp = 0.f;
            for (int c = 0; c < Cn; ++c) { m += sh_mean[b * 3 + c]; tp += sh_temp[b * 3 + c]; }
            m *= (1.0f / 3.0f); tp *= (1.0f / 3.0f);
            sh_mln[b] = m; sh_vln[b] = tp - m * m;
        }
        for (int c = 0; c < Cn; ++c) {
            float m = 0.f, tp = 0.f;
            for (int b = 0; b < Bn; ++b) { m += sh_mean[b * 3 + c]; tp += sh_temp[b * 3 + c]; }
            m *= 0.125f; tp *= 0.125f;
            sh_mbn[c] = m; sh_vbn[c] = tp - m * m;
        }
        {
            float m0 = mean_w[0], m1 = mean_w[1], m2 = mean_w[2];
            float mm = fmaxf(m0, fmaxf(m1, m2));
            float e0 = __expf(m0 - mm), e1 = __expf(m1 - mm), e2 = __expf(m2 - mm);
            float inv = 1.0f / (e0 + e1 + e2);
            sh_mw[0] = e0 * inv; sh_mw[1] = e1 * inv; sh_mw[2] = e2 * inv;
        }
        {
            float v0 = var_w[0], v1 = var_w[1], v2 = var_w[2];
            float vm = fmaxf(v0, fmaxf(v1, v2));
            float e0 = __expf(v0 - vm), e1 = __expf(v1 - vm), e2 = __expf(v2 - vm);
            float inv = 1.0f / (e0 + e1 + e2);
            sh_vw[0] = e0 * inv; sh_vw[1] = e1 * inv; sh_vw[2] = e2 * inv;
        }
    }
    __syncthreads();
    if (tid < 24) {
        int b = tid / 3, c = tid % 3;
        float mean = sh_mw[0] * sh_mean[tid] + sh_mw[1] * sh_mln[b] + sh_mw[2] * sh_mbn[c];
        float var  = sh_vw[0] * sh_var[tid]  + sh_vw[1] * sh_vln[b] + sh_vw[2] * sh_vbn[c];
        float inv = 1.0f / sqrtf(var + EPSn);
        float sc = inv * snw[c];
        float sf = snb[c] - mean * sc;
        sh_scale[tid] = sc; sh_shift[tid] = sf;
        scale[tid] = sc; shift[tid] = sf;
    }
    __syncthreads();
    for (int i = tid; i < Bn * Cn * Tn; i += 256) {
        int bc = i >> 5;
        kvt0[i] = sh_scale[bc] * kvt0[i] + sh_shift[bc] * sWt0;
        kvt1[i] = sh_scale[bc] * kvt1[i] + sh_shift[bc] * sWt1;
    }
    __syncthreads();
    if (tid < 24) {
        float m = -3.4e38f;
        for (int t = 0; t < Tn; ++t) m = fmaxf(m, kvt0[tid * Tn + t]);
        float se = 0.f;
        for (int t = 0; t < Tn; ++t) se += __expf(kvt0[tid * Tn + t] - m);
        float inv = 1.0f / se;
        for (int t = 0; t < Tn; ++t)
            A[tid * Tn + t] = sqrtf(__expf(kvt0[tid * Tn + t] - m) * inv) * kvt1[tid * Tn + t];
    }
}

// ========== K5a: per-chunk max/expsum of the s-softmax input (halves summed) ==========
__global__ __launch_bounds__(256) void k5a_maxsum(
    const float* __restrict__ raw0, const float* __restrict__ scale,
    const float* __restrict__ shift, const float* __restrict__ wsum,
    float2* __restrict__ ms)
{
    const int ch = blockIdx.x;   // 0..7 (chunks of 2048)
    const int bc = blockIdx.y;   // 0..23
    const int tid = threadIdx.x, lane = tid & 63, wave = tid >> 6;
    const float sc = scale[bc], c0 = shift[bc] * wsum[2];
    const float* pa = raw0 + (size_t)bc * HWn + ch * 2048 + tid * 8;
    const float* pb = pa + (size_t)24 * HWn;
    float4 a0_ = ((const float4*)pa)[0], a1_ = ((const float4*)pa)[1];
    float4 b0_ = ((const float4*)pb)[0], b1_ = ((const float4*)pb)[1];
    float vals[8] = { a0_.x + b0_.x, a0_.y + b0_.y, a0_.z + b0_.z, a0_.w + b0_.w,
                      a1_.x + b1_.x, a1_.y + b1_.y, a1_.z + b1_.z, a1_.w + b1_.w };
    float m = -3.4e38f;
#pragma unroll
    for (int i = 0; i < 8; ++i) m = fmaxf(m, sc * vals[i] + c0);
#pragma unroll
    for (int d = 1; d < 64; d <<= 1) m = fmaxf(m, __shfl_xor(m, d, 64));
    __shared__ float wm[4], wsm[4];
    if (lane == 0) wm[wave] = m;
    __syncthreads();
    const float M = fmaxf(fmaxf(wm[0], wm[1]), fmaxf(wm[2], wm[3]));
    float s = 0.f;
#pragma unroll
    for (int i = 0; i < 8; ++i) s += __expf(sc * vals[i] + c0 - M);
#pragma unroll
    for (int d = 1; d < 64; d <<= 1) s += __shfl_xor(s, d, 64);
    if (lane == 0) wsm[wave] = s;
    __syncthreads();
    if (tid == 0) {
        float2 o; o.x = M; o.y = wsm[0] + wsm[1] + wsm[2] + wsm[3];
        ms[bc * 8 + ch] = o;
    }
}

// ========== K6: B finalize inline + outer product out[bc,t,s] = A[t]*B[s] ==========
__global__ __launch_bounds__(256) void k6_outer(
    const float* __restrict__ raw0, const float* __restrict__ raw1,
    const float* __restrict__ scale, const float* __restrict__ shift,
    const float* __restrict__ wsum, const float2* __restrict__ ms,
    const float* __restrict__ A, float* __restrict__ out)
{
    const int ch = blockIdx.x;   // 0..15 (chunks of 1024)
    const int bc = blockIdx.y;   // 0..23
    const int tid = threadIdx.x;
    __shared__ float a[Tn];
    if (tid < Tn) a[tid] = A[bc * Tn + tid];
    const float sc = scale[bc], sf = shift[bc];
    const float c0 = sf * wsum[2], c1 = sf * wsum[3];
    float M = -3.4e38f;
#pragma unroll
    for (int j = 0; j < 8; ++j) M = fmaxf(M, ms[bc * 8 + j].x);
    float S = 0.f;
#pragma unroll
    for (int j = 0; j < 8; ++j) S += ms[bc * 8 + j].y * __expf(ms[bc * 8 + j].x - M);
    const float invS = 1.0f / S;
    const int s = ch * 1024 + tid * 4;
    const float* p0a = raw0 + (size_t)bc * HWn + s;
    const float* p1a = raw1 + (size_t)bc * HWn + s;
    float4 r0a = *(const float4*)p0a, r0b = *(const float4*)(p0a + (size_t)24 * HWn);
    float4 r1a = *(const float4*)p1a, r1b = *(const float4*)(p1a + (size_t)24 * HWn);
    float4 r0, r1;
    r0.x = r0a.x + r0b.x; r0.y = r0a.y + r0b.y; r0.z = r0a.z + r0b.z; r0.w = r0a.w + r0b.w;
    r1.x = r1a.x + r1b.x; r1.y = r1a.y + r1b.y; r1.z = r1a.z + r1b.z; r1.w = r1a.w + r1b.w;
    float4 Bv;
    Bv.x = sqrtf(__expf(sc * r0.x + c0 - M) * invS) * (sc * r1.x + c1);
    Bv.y = sqrtf(__expf(sc * r0.y + c0 - M) * invS) * (sc * r1.y + c1);
    Bv.z = sqrtf(__expf(sc * r0.z + c0 - M) * invS) * (sc * r1.z + c1);
    Bv.w = sqrtf(__expf(sc * r0.w + c0 - M) * invS) * (sc * r1.w + c1);
    __syncthreads();
    float* op = out + (size_t)bc * Nn + s;
#pragma unroll
    for (int t = 0; t < Tn; ++t) {
        const float av = a[t];
        float4 o; o.x = av * Bv.x; o.y = av * Bv.y; o.z = av * Bv.z; o.w = av * Bv.w;
        *(float4*)(op + (size_t)t * HWn) = o;
    }
}

extern "C" void kernel_launch(void* const* d_in, const int* in_sizes, int n_in,
                              void* d_out, int out_size, void* d_ws, size_t ws_size,
                              hipStream_t stream) {
    const float* x          = (const float*)d_in[0];
    const float* w_spatial  = (const float*)d_in[1];
    const float* b_spatial  = (const float*)d_in[2];
    const float* w_temporal = (const float*)d_in[3];
    const float* b_temporal = (const float*)d_in[4];
    const float* sn_weight  = (const float*)d_in[5];
    const float* sn_bias    = (const float*)d_in[6];
    const float* mean_weight= (const float*)d_in[7];
    const float* var_weight = (const float*)d_in[8];
    const float* w_kv_s     = (const float*)d_in[9];
    const float* w_kv_t     = (const float*)d_in[10];
    float* out = (float*)d_out;
    float* ws  = (float*)d_ws;

    // ws layout (floats)
    float* raw0  = ws;                                  // [2][24][HWn] = 786432
    float* raw1  = raw0 + 2 * (size_t)Bn * Cn * HWn;    // 786432
    float* pt0p  = raw1 + 2 * (size_t)Bn * Cn * HWn;    // 24*32*32 = 24576
    float* pt1p  = pt0p + (size_t)Bn * Cn * Tn * RTn;   // 24576
    float* ss0p  = pt1p + (size_t)Bn * Cn * Tn * RTn;   // 24*64 = 1536
    float* ss1p  = ss0p + (size_t)Bn * Cn * RTn * 2;    // 1536
    float* scale = ss1p + (size_t)Bn * Cn * RTn * 2;    // 24
    float* shift = scale + 24;                          // 24
    float* A     = shift + 24;                          // 768
    float* wsum  = A + Bn * Cn * Tn;                    // 4
    float2* ms   = (float2*)(wsum + 4);                 // 192 float2

    k12_conv<<<dim3(RTn, Bn, 2), 256, 0, stream>>>(x, w_spatial, b_spatial,
                                                   w_temporal, b_temporal,
                                                   w_kv_t, w_kv_s,
                                                   raw0, raw1, pt0p, pt1p, ss0p, ss1p);
    k3_finalize<<<1, 256, 0, stream>>>(pt0p, pt1p, ss0p, ss1p,
                                       mean_weight, var_weight, sn_weight, sn_bias,
                                       w_kv_t, w_kv_s, scale, shift, A, wsum);
    k5a_maxsum<<<dim3(8, Bn * Cn), 256, 0, stream>>>(raw0, scale, shift, wsum, ms);
    k6_outer<<<dim3(16, Bn * Cn), 256, 0, stream>>>(raw0, raw1, scale, shift, wsum,
                                                    ms, A, out);
}